// Round 1
// baseline (376.839 us; speedup 1.0000x reference)
//
#include <hip/hip_runtime.h>
#include <hip/hip_bf16.h>
#include <math.h>

#define B_      4
#define IN_DIM  512
#define HID     1024
#define SEQ     4096
#define RH      64
#define RL      2
#define MID_DIM 12352          // 2*64*64 + 65*64
#define OUT_DIM 193            // 2*64 + 65
#define MLP_OUT 24897          // RL*MID_DIM + OUT_DIM
#define MLP_STRIDE 24904       // padded row stride for mlp_out buffer
#define INV2PI  0.15915494309189535f

// ---- workspace layout (float offsets) ----
#define OFF_P0   0                         // 2 * 4096
#define OFF_P1   8192                      // 4 * 4096
#define OFF_H1   24576                     // 4096
#define OFF_P2   28672                     // 4 * 4096
#define OFF_H2   45056                     // 4096
#define OFF_P3   49152                     // 4*4*MLP_OUT = 398352
#define OFF_MLP  447504                    // 4*MLP_STRIDE = 99616
#define OFF_R1   547120                    // 4*64*4096 = 1048576
#define OFF_R2   1595696                   // 1048576

__device__ __forceinline__ float gelu_exact(float v) {
    return 0.5f * v * (1.0f + erff(v * 0.70710678118654752f));
}

__device__ __forceinline__ float hw_sin_rev(float r) {
    // r in revolutions; reduce to [-0.5,0.5], v_sin_f32 computes sin(2*pi*x)
    r = r - __builtin_rintf(r);
    return __builtin_amdgcn_sinf(r);
}

// ---------- stage A: x @ w0, K-split 2, partials (no bias/gelu yet) ----------
__global__ void k_gemm0(const float* __restrict__ x, const float* __restrict__ w0,
                        float* __restrict__ p0) {
    const int bx = blockIdx.x;          // 8: cchunk(4) x kc(2)
    const int cch = bx >> 1, kc = bx & 1;
    const int b = blockIdx.y;
    __shared__ float xs[256];
    xs[threadIdx.x] = x[b * IN_DIM + kc * 256 + threadIdx.x];
    __syncthreads();
    const int c = cch * 256 + threadIdx.x;
    float acc = 0.f;
    #pragma unroll 4
    for (int k = 0; k < 256; ++k)
        acc = fmaf(xs[k], w0[(size_t)(kc * 256 + k) * HID + c], acc);
    p0[kc * 4096 + b * HID + c] = acc;
}

// ---------- h0=gelu(p0+b0) staged in LDS, then @ w (K-split 4) ----------
__global__ void k_gemm1(const float* __restrict__ p0, const float* __restrict__ b0,
                        const float* __restrict__ w, float* __restrict__ pout) {
    const int bx = blockIdx.x;          // 16: cchunk(4) x kc(4)
    const int cch = bx >> 2, kc = bx & 3;
    const int b = blockIdx.y;
    __shared__ float hs[256];
    {
        const int kk = kc * 256 + threadIdx.x;
        float g = p0[b * HID + kk] + p0[4096 + b * HID + kk] + b0[kk];
        hs[threadIdx.x] = gelu_exact(g);
    }
    __syncthreads();
    const int c = cch * 256 + threadIdx.x;
    float acc = 0.f;
    #pragma unroll 4
    for (int k = 0; k < 256; ++k)
        acc = fmaf(hs[k], w[(size_t)(kc * 256 + k) * HID + c], acc);
    pout[kc * 4096 + b * HID + c] = acc;
}

// ---------- same but input row already materialized (h1) ----------
__global__ void k_gemm2(const float* __restrict__ h, const float* __restrict__ w,
                        float* __restrict__ pout) {
    const int bx = blockIdx.x;
    const int cch = bx >> 2, kc = bx & 3;
    const int b = blockIdx.y;
    __shared__ float hs[256];
    hs[threadIdx.x] = h[b * HID + kc * 256 + threadIdx.x];
    __syncthreads();
    const int c = cch * 256 + threadIdx.x;
    float acc = 0.f;
    #pragma unroll 4
    for (int k = 0; k < 256; ++k)
        acc = fmaf(hs[k], w[(size_t)(kc * 256 + k) * HID + c], acc);
    pout[kc * 4096 + b * HID + c] = acc;
}

// ---------- combine 4 K-partials + bias, layernorm, gelu ----------
__global__ void k_ln_gelu(const float* __restrict__ part, const float* __restrict__ bias,
                          const float* __restrict__ g, const float* __restrict__ bln,
                          float* __restrict__ out) {
    const int b = blockIdx.x;
    const int tid = threadIdx.x;
    __shared__ float r1[256], r2[256], s_mu, s_rstd;
    float y[4];
    float s1 = 0.f, s2 = 0.f;
    #pragma unroll
    for (int j = 0; j < 4; ++j) {
        const int c = j * 256 + tid;
        float v = part[b * HID + c] + part[4096 + b * HID + c] +
                  part[8192 + b * HID + c] + part[12288 + b * HID + c] + bias[c];
        y[j] = v; s1 += v; s2 += v * v;
    }
    r1[tid] = s1; r2[tid] = s2;
    __syncthreads();
    for (int off = 128; off > 0; off >>= 1) {
        if (tid < off) { r1[tid] += r1[tid + off]; r2[tid] += r2[tid + off]; }
        __syncthreads();
    }
    if (tid == 0) {
        float mu = r1[0] * (1.0f / HID);
        float var = r2[0] * (1.0f / HID) - mu * mu;
        s_mu = mu; s_rstd = rsqrtf(var + 1e-5f);
    }
    __syncthreads();
    const float mu = s_mu, rstd = s_rstd;
    #pragma unroll
    for (int j = 0; j < 4; ++j) {
        const int c = j * 256 + tid;
        float v = (y[j] - mu) * rstd * g[c] + bln[c];
        out[b * HID + c] = gelu_exact(v);
    }
}

// ---------- fat gemm: h2(4x1024) @ w3(1024xMLP_OUT), K-split 4, all b per block ----------
__global__ void k_gemm3(const float* __restrict__ h2, const float* __restrict__ w3,
                        float* __restrict__ part3) {
    const int bx = blockIdx.x;           // 98*4
    const int cch = bx >> 2, kc = bx & 3;
    __shared__ float hs[1024];
    for (int e = threadIdx.x; e < 1024; e += 256) {
        const int b = e >> 8, kk = e & 255;
        hs[e] = h2[b * HID + kc * 256 + kk];
    }
    __syncthreads();
    const int c = cch * 256 + threadIdx.x;
    if (c >= MLP_OUT) return;
    float a0 = 0.f, a1 = 0.f, a2 = 0.f, a3 = 0.f;
    #pragma unroll 4
    for (int k = 0; k < 256; ++k) {
        const float w = w3[(size_t)(kc * 256 + k) * MLP_OUT + c];
        a0 = fmaf(hs[k], w, a0);
        a1 = fmaf(hs[256 + k], w, a1);
        a2 = fmaf(hs[512 + k], w, a2);
        a3 = fmaf(hs[768 + k], w, a3);
    }
    part3[(size_t)(kc * 4 + 0) * MLP_OUT + c] = a0;
    part3[(size_t)(kc * 4 + 1) * MLP_OUT + c] = a1;
    part3[(size_t)(kc * 4 + 2) * MLP_OUT + c] = a2;
    part3[(size_t)(kc * 4 + 3) * MLP_OUT + c] = a3;
}

__global__ void k_comb3(const float* __restrict__ part3, const float* __restrict__ b3,
                        float* __restrict__ mlp) {
    const int c = blockIdx.x * 256 + threadIdx.x;
    const int b = blockIdx.y;
    if (c >= MLP_OUT) return;
    float a = b3[c];
    #pragma unroll
    for (int kc = 0; kc < 4; ++kc) a += part3[(size_t)(kc * 4 + b) * MLP_OUT + c];
    mlp[(size_t)b * MLP_STRIDE + c] = a;
}

// ---------- ripple middle layer: out[b][o][t] = gelu(batch_ripple) ----------
// lane = o; each wave handles 8 t's; block: 32 t x 64 o for one b.
__global__ void k_ripple(const float* __restrict__ mlp, const float* __restrict__ xin,
                         const float* __restrict__ lcw, const float* __restrict__ lcb,
                         float* __restrict__ rout, int layer) {
    const int tid = threadIdx.x;
    const int b = blockIdx.y;
    const int t0 = blockIdx.x * 32;
    const float* mw = mlp + (size_t)b * MLP_STRIDE + layer * MID_DIM;

    __shared__ __align__(16) float s_wsc[4096];  // [i][o]  w0/2pi
    __shared__ __align__(16) float s_wof[4096];  // [i][o]  w1/2pi
    __shared__ __align__(16) float s_bsv[4096];  // [i][o]  b_sin
    __shared__ float s_bc[64];
    __shared__ __align__(16) float s_x[2080];    // phase1: xT[i][32]; phase2: outT[t][65]

    for (int e = tid; e < 4096; e += 256) {
        const int o = e >> 6, i = e & 63;
        s_wsc[i * 64 + o] = mw[o * 128 + i * 2] * INV2PI;
        s_wof[i * 64 + o] = mw[o * 128 + i * 2 + 1] * INV2PI;
        s_bsv[i * 64 + o] = mw[8192 + o * 65 + 1 + i];
    }
    if (tid < 64) s_bc[tid] = mw[8192 + tid * 65];

    if (layer == 0) {
        for (int e = tid; e < 2048; e += 256) {
            const int i = e >> 5, tt = e & 31;
            s_x[i * 32 + tt] = fmaf((float)(t0 + tt), lcw[i], lcb[i]);
        }
    } else {
        for (int e = tid; e < 2048; e += 256) {
            const int i = e >> 5, tt = e & 31;
            s_x[i * 32 + tt] = xin[(size_t)(b * 64 + i) * SEQ + t0 + tt];
        }
    }
    __syncthreads();

    const int lane = tid & 63;
    const int wid = tid >> 6;
    const int tb = wid * 8;
    float acc[8];
    {
        const float bc = s_bc[lane];
        #pragma unroll
        for (int t = 0; t < 8; ++t) acc[t] = bc;
    }
    for (int i = 0; i < 64; ++i) {
        const float ws = s_wsc[i * 64 + lane];
        const float wo = s_wof[i * 64 + lane];
        const float bs = s_bsv[i * 64 + lane];
        const float4 xa = *(const float4*)&s_x[i * 32 + tb];
        const float4 xb = *(const float4*)&s_x[i * 32 + tb + 4];
        const float xv[8] = {xa.x, xa.y, xa.z, xa.w, xb.x, xb.y, xb.z, xb.w};
        #pragma unroll
        for (int t = 0; t < 8; ++t) {
            float r = fmaf(ws, xv[t], wo);
            acc[t] = fmaf(hw_sin_rev(r), bs, acc[t]);
        }
    }
    __syncthreads();   // done reading s_x
    #pragma unroll
    for (int t = 0; t < 8; ++t)
        s_x[(tb + t) * 65 + lane] = gelu_exact(acc[t]);   // outT[t][65]
    __syncthreads();
    for (int e = tid; e < 2048; e += 256) {
        const int o = e >> 5, tt = e & 31;
        rout[(size_t)(b * 64 + o) * SEQ + t0 + tt] = s_x[tt * 65 + o];
    }
}

// ---------- final: out ripple (RH_out=1) + bypass, write [b][t] ----------
__global__ void k_final(const float* __restrict__ mlp, const float* __restrict__ r2,
                        const float* __restrict__ lcw, const float* __restrict__ lcb,
                        const float* __restrict__ bypw, const float* __restrict__ bypb,
                        float* __restrict__ out) {
    const int t = blockIdx.x * 256 + threadIdx.x;
    const int b = blockIdx.y;
    const float* ow = mlp + (size_t)b * MLP_STRIDE + RL * MID_DIM;
    float acc = ow[128];
    #pragma unroll 4
    for (int i = 0; i < 64; ++i) {
        const float w0 = ow[i * 2] * INV2PI;
        const float w1 = ow[i * 2 + 1] * INV2PI;
        const float bs = ow[129 + i];
        const float xv = r2[(size_t)(b * 64 + i) * SEQ + t];
        float r = fmaf(w0, xv, w1);
        acc = fmaf(hw_sin_rev(r), bs, acc);
    }
    // bypass (same for all b, recompute)
    const float bw0 = bypw[0] * INV2PI, bw1 = bypw[1] * INV2PI;
    const float bb1 = bypb[1];
    float bacc = bypb[0];
    #pragma unroll 4
    for (int j = 0; j < 64; ++j) {
        const float xv = fmaf((float)t, lcw[j], lcb[j]);
        float r = fmaf(bw0, xv, bw1);
        bacc = fmaf(hw_sin_rev(r), bb1, bacc);
    }
    out[(size_t)b * SEQ + t] = acc + bacc;
}

extern "C" void kernel_launch(void* const* d_in, const int* in_sizes, int n_in,
                              void* d_out, int out_size, void* d_ws, size_t ws_size,
                              hipStream_t stream) {
    const float* x     = (const float*)d_in[0];
    const float* w0    = (const float*)d_in[1];
    const float* b0    = (const float*)d_in[2];
    const float* w1    = (const float*)d_in[3];
    const float* b1    = (const float*)d_in[4];
    const float* g1    = (const float*)d_in[5];
    const float* bln1  = (const float*)d_in[6];
    const float* w2    = (const float*)d_in[7];
    const float* b2    = (const float*)d_in[8];
    const float* g2    = (const float*)d_in[9];
    const float* bln2  = (const float*)d_in[10];
    const float* w3    = (const float*)d_in[11];
    const float* b3    = (const float*)d_in[12];
    const float* lcw   = (const float*)d_in[13];
    const float* lcb   = (const float*)d_in[14];
    const float* bypw  = (const float*)d_in[15];
    const float* bypb  = (const float*)d_in[16];
    float* out = (float*)d_out;
    float* ws  = (float*)d_ws;

    float* p0   = ws + OFF_P0;
    float* p1   = ws + OFF_P1;
    float* h1   = ws + OFF_H1;
    float* p2   = ws + OFF_P2;
    float* h2   = ws + OFF_H2;
    float* p3   = ws + OFF_P3;
    float* mlp  = ws + OFF_MLP;
    float* r1   = ws + OFF_R1;
    float* r2   = ws + OFF_R2;

    k_gemm0<<<dim3(8, B_), 256, 0, stream>>>(x, w0, p0);
    k_gemm1<<<dim3(16, B_), 256, 0, stream>>>(p0, b0, w1, p1);
    k_ln_gelu<<<B_, 256, 0, stream>>>(p1, b1, g1, bln1, h1);
    k_gemm2<<<dim3(16, B_), 256, 0, stream>>>(h1, w2, p2);
    k_ln_gelu<<<B_, 256, 0, stream>>>(p2, b2, g2, bln2, h2);
    k_gemm3<<<392, 256, 0, stream>>>(h2, w3, p3);
    k_comb3<<<dim3(98, B_), 256, 0, stream>>>(p3, b3, mlp);
    k_ripple<<<dim3(SEQ / 32, B_), 256, 0, stream>>>(mlp, nullptr, lcw, lcb, r1, 0);
    k_ripple<<<dim3(SEQ / 32, B_), 256, 0, stream>>>(mlp, r1, lcw, lcb, r2, 1);
    k_final<<<dim3(SEQ / 256, B_), 256, 0, stream>>>(mlp, r2, lcw, lcb, bypw, bypb, out);
}

// Round 2
// 253.531 us; speedup vs baseline: 1.4864x; 1.4864x over previous
//
#include <hip/hip_runtime.h>
#include <hip/hip_bf16.h>
#include <math.h>

#define B_      4
#define IN_DIM  512
#define HID     1024
#define SEQ     4096
#define RH      64
#define RL      2
#define MID_DIM 12352          // 2*64*64 + 65*64
#define OUT_DIM 193            // 2*64 + 65
#define MLP_OUT 24897          // RL*MID_DIM + OUT_DIM
#define INV2PI  0.15915494309189535f

// transposed/pre-scaled weight layout, per b (stride MLPT_STRIDE):
//  layer l in {0,1} at l*12416:
//    [0,4096)      wsc[i][o]   = w0/2pi
//    [4096,8192)   wof[i][o]   = w1/2pi
//    [8192,12288)  bsv[i][o]   = b_sin
//    [12288,12352) bc[o]
//    [12352,12416) pad
//  out layer at 24832:
//    [0,64) wsO/2pi  [64,128) woO/2pi  [128,192) bsO  [192] bcO  pad to 256
#define MLPT_STRIDE 25088

// ---- workspace layout (float offsets) ----
#define OFF_P0    0            // 8*4*1024   = 32768
#define OFF_P1    32768        // 16*4*1024  = 65536
#define OFF_H1    98304        // 4096
#define OFF_P2    102400       // 16*4*1024  = 65536
#define OFF_H2    167936       // 4096
#define OFF_P3    172032       // 8*4*24897  = 796704
#define OFF_MLPT  968736       // 4*25088    = 100352  (div by 4 -> 16B aligned)

__device__ __forceinline__ float gelu_exact(float v) {
    return 0.5f * v * (1.0f + erff(v * 0.70710678118654752f));
}

__device__ __forceinline__ float hw_sin_rev(float r) {
    r = r - __builtin_rintf(r);
    return __builtin_amdgcn_sinf(r);
}

// ---------- x(4x512) @ w0(512x1024): grid (cch=16, kc=8), block 256 = 4b x 64c ----------
__global__ void k_gemm0(const float* __restrict__ x, const float* __restrict__ w0,
                        float* __restrict__ p0) {
    const int cch = blockIdx.x;
    const int kc  = blockIdx.y;
    const int tid = threadIdx.x;
    __shared__ float xs[256];                 // [b][k]
    {
        const int b = tid >> 6, k = tid & 63;
        xs[tid] = x[b * IN_DIM + kc * 64 + k];
    }
    __syncthreads();
    const int b = tid >> 6, cl = tid & 63;
    const int c = cch * 64 + cl;
    const float* wp = w0 + (size_t)(kc * 64) * HID + c;
    const float* xp = xs + b * 64;
    float acc = 0.f;
    #pragma unroll 8
    for (int k = 0; k < 64; ++k)
        acc = fmaf(xp[k], wp[(size_t)k * HID], acc);
    p0[(kc * 4 + b) * HID + c] = acc;
}

// ---------- h0=gelu(sum8 p0 + b0); h0 @ w1: grid (cch=16, kc=16), block 256 ----------
__global__ void k_gemm1(const float* __restrict__ p0, const float* __restrict__ b0,
                        const float* __restrict__ w1, float* __restrict__ p1) {
    const int cch = blockIdx.x;
    const int kc  = blockIdx.y;
    const int tid = threadIdx.x;
    __shared__ float hs[256];                 // [b][k]
    {
        const int b = tid >> 6, k = tid & 63;
        const int kg = kc * 64 + k;
        float v = b0[kg];
        #pragma unroll
        for (int j = 0; j < 8; ++j) v += p0[(j * 4 + b) * HID + kg];
        hs[tid] = gelu_exact(v);
    }
    __syncthreads();
    const int b = tid >> 6, cl = tid & 63;
    const int c = cch * 64 + cl;
    const float* wp = w1 + (size_t)(kc * 64) * HID + c;
    const float* hp = hs + b * 64;
    float acc = 0.f;
    #pragma unroll 8
    for (int k = 0; k < 64; ++k)
        acc = fmaf(hp[k], wp[(size_t)k * HID], acc);
    p1[(kc * 4 + b) * HID + c] = acc;
}

// ---------- h(4x1024) @ w: grid (cch=16, kc=16), block 256 (input already dense) ----------
__global__ void k_gemm2(const float* __restrict__ h, const float* __restrict__ w,
                        float* __restrict__ pout) {
    const int cch = blockIdx.x;
    const int kc  = blockIdx.y;
    const int tid = threadIdx.x;
    __shared__ float hs[256];
    {
        const int b = tid >> 6, k = tid & 63;
        hs[tid] = h[b * HID + kc * 64 + k];
    }
    __syncthreads();
    const int b = tid >> 6, cl = tid & 63;
    const int c = cch * 64 + cl;
    const float* wp = w + (size_t)(kc * 64) * HID + c;
    const float* hp = hs + b * 64;
    float acc = 0.f;
    #pragma unroll 8
    for (int k = 0; k < 64; ++k)
        acc = fmaf(hp[k], wp[(size_t)k * HID], acc);
    pout[(kc * 4 + b) * HID + c] = acc;
}

// ---------- combine 16 partials + bias -> LN -> gelu: grid 4, block 1024 ----------
__global__ void k_lng(const float* __restrict__ part, const float* __restrict__ bias,
                      const float* __restrict__ g, const float* __restrict__ bl,
                      float* __restrict__ h) {
    const int b = blockIdx.x, tid = threadIdx.x;
    float v = bias[tid];
    #pragma unroll
    for (int j = 0; j < 16; ++j) v += part[(j * 4 + b) * HID + tid];
    float s1 = v, s2 = v * v;
    #pragma unroll
    for (int m = 1; m < 64; m <<= 1) {
        s1 += __shfl_xor(s1, m, 64);
        s2 += __shfl_xor(s2, m, 64);
    }
    __shared__ float r1[16], r2[16], s_mu, s_rs;
    const int lane = tid & 63, wid = tid >> 6;
    if (lane == 0) { r1[wid] = s1; r2[wid] = s2; }
    __syncthreads();
    if (tid == 0) {
        float a = 0.f, c = 0.f;
        #pragma unroll
        for (int j = 0; j < 16; ++j) { a += r1[j]; c += r2[j]; }
        const float mu = a * (1.0f / HID);
        s_mu = mu;
        s_rs = rsqrtf(c * (1.0f / HID) - mu * mu + 1e-5f);
    }
    __syncthreads();
    h[b * HID + tid] = gelu_exact((v - s_mu) * s_rs * g[tid] + bl[tid]);
}

// ---------- h2(4x1024) @ w3(1024xMLP_OUT): grid (cch=98, kc=8), block 256 ----------
__global__ void k_gemm3(const float* __restrict__ h2, const float* __restrict__ w3,
                        float* __restrict__ p3) {
    const int cch = blockIdx.x;
    const int kc  = blockIdx.y;
    const int tid = threadIdx.x;
    __shared__ float hs[512];                 // [b][128]
    for (int e = tid; e < 512; e += 256) {
        const int b = e >> 7, k = e & 127;
        hs[e] = h2[b * HID + kc * 128 + k];
    }
    __syncthreads();
    const int c = cch * 256 + tid;
    if (c >= MLP_OUT) return;
    const float* wp = w3 + (size_t)(kc * 128) * MLP_OUT + c;
    float a0 = 0.f, a1 = 0.f, a2 = 0.f, a3 = 0.f;
    #pragma unroll 16
    for (int k = 0; k < 128; ++k) {
        const float w = wp[(size_t)k * MLP_OUT];
        a0 = fmaf(hs[k],       w, a0);
        a1 = fmaf(hs[128 + k], w, a1);
        a2 = fmaf(hs[256 + k], w, a2);
        a3 = fmaf(hs[384 + k], w, a3);
    }
    p3[(size_t)(kc * 4 + 0) * MLP_OUT + c] = a0;
    p3[(size_t)(kc * 4 + 1) * MLP_OUT + c] = a1;
    p3[(size_t)(kc * 4 + 2) * MLP_OUT + c] = a2;
    p3[(size_t)(kc * 4 + 3) * MLP_OUT + c] = a3;
}

// ---------- combine 8 partials + bias -> transposed, pre-scaled layout ----------
__global__ void k_comb3T(const float* __restrict__ p3, const float* __restrict__ b3,
                         float* __restrict__ mlpT) {
    const int d = blockIdx.x * 256 + threadIdx.x;   // < 25088
    const int b = blockIdx.y;
    int src = -1;
    float scale = 1.f;
    if (d < 24832) {
        const int l = d / 12416, r = d % 12416;
        const int base = l * MID_DIM;
        if (r < 8192) {                       // wsc / wof
            const int half = r >> 12;
            const int rr = r & 4095;
            const int i = rr >> 6, o = rr & 63;
            src = base + o * 128 + i * 2 + half;
            scale = INV2PI;
        } else if (r < 12288) {               // bsv
            const int rr = r - 8192;
            const int i = rr >> 6, o = rr & 63;
            src = base + 8192 + o * 65 + 1 + i;
        } else if (r < 12352) {               // bc
            const int o = r - 12288;
            src = base + 8192 + o * 65;
        }
    } else {
        const int rr = d - 24832;
        const int base = RL * MID_DIM;        // 24704
        if (rr < 64)        { src = base + rr * 2;            scale = INV2PI; }
        else if (rr < 128)  { src = base + (rr - 64) * 2 + 1; scale = INV2PI; }
        else if (rr < 192)  { src = base + 128 + 1 + (rr - 128); }
        else if (rr == 192) { src = base + 128; }
    }
    float v = 0.f;
    if (src >= 0) {
        v = b3[src];
        #pragma unroll
        for (int j = 0; j < 8; ++j) v += p3[(size_t)(j * 4 + b) * MLP_OUT + src];
        v *= scale;
    }
    mlpT[(size_t)b * MLPT_STRIDE + d] = v;
}

// ---------- fully fused ripple: layer0 -> layer1 -> out-layer + bypass ----------
// grid (SEQ/32, B), block 256 (4 waves x 8 t). lane = o. No intermediate global traffic.
__global__ void __launch_bounds__(256, 2) k_ripple(
        const float* __restrict__ mlpT, const float* __restrict__ lcw,
        const float* __restrict__ lcb, const float* __restrict__ bypw,
        const float* __restrict__ bypb, float* __restrict__ out) {
    const int tid = threadIdx.x;
    const int b = blockIdx.y;
    const int t0 = blockIdx.x * 32;
    const int lane = tid & 63, wid = tid >> 6, tb = wid * 8;

    __shared__ __align__(16) float s_w[12416];   // current layer weights (transposed, scaled)
    __shared__ __align__(16) float s_x[64 * 36]; // x[i][t], stride 36 (16B-aligned, few conflicts)
    __shared__ __align__(16) float s_wo[256];    // out-layer weights
    __shared__ float s_red[32];

    const float* mb = mlpT + (size_t)b * MLPT_STRIDE;

    {   // stage layer-0 weights + out weights (flat float4 copy)
        const float4* src = reinterpret_cast<const float4*>(mb);
        float4* dst = reinterpret_cast<float4*>(s_w);
        for (int e = tid; e < 3104; e += 256) dst[e] = src[e];
        if (tid < 64) {
            reinterpret_cast<float4*>(s_wo)[tid] =
                reinterpret_cast<const float4*>(mb + 24832)[tid];
        }
    }
    const float lw = lcw[lane], lb = lcb[lane];   // for bypass
    // init x[i][t] = t*lcw[i] + lcb[i]
    for (int e = tid; e < 2048; e += 256) {
        const int i = e >> 5, tt = e & 31;
        s_x[i * 36 + tt] = fmaf((float)(t0 + tt), lcw[i], lcb[i]);
    }
    __syncthreads();

    float acc[8];
    for (int layer = 0; layer < 2; ++layer) {
        const float bc = s_w[12288 + lane];
        #pragma unroll
        for (int j = 0; j < 8; ++j) acc[j] = bc;
        for (int i = 0; i < 64; ++i) {
            const float ws = s_w[i * 64 + lane];
            const float wo = s_w[4096 + i * 64 + lane];
            const float bs = s_w[8192 + i * 64 + lane];
            const float4 xa = *reinterpret_cast<const float4*>(&s_x[i * 36 + tb]);
            const float4 xb = *reinterpret_cast<const float4*>(&s_x[i * 36 + tb + 4]);
            const float xv[8] = {xa.x, xa.y, xa.z, xa.w, xb.x, xb.y, xb.z, xb.w};
            #pragma unroll
            for (int j = 0; j < 8; ++j) {
                const float r = fmaf(ws, xv[j], wo);
                acc[j] = fmaf(hw_sin_rev(r), bs, acc[j]);
            }
        }
        __syncthreads();               // everyone done reading s_w / s_x
        if (layer == 0) {
            // write gelu(out) transposed: lane(=o) becomes next layer's i
            #pragma unroll
            for (int j = 0; j < 8; ++j)
                s_x[lane * 36 + tb + j] = gelu_exact(acc[j]);
            // stage layer-1 weights
            const float4* src = reinterpret_cast<const float4*>(mb + 12416);
            float4* dst = reinterpret_cast<float4*>(s_w);
            for (int e = tid; e < 3104; e += 256) dst[e] = src[e];
            __syncthreads();
        }
    }

    // final: out-layer ripple + bypass, 64-lane butterfly reduction per t
    {
        const float wsO = s_wo[lane], woO = s_wo[64 + lane], bsO = s_wo[128 + lane];
        const float bcO = s_wo[192];
        const float bw0 = bypw[0] * INV2PI, bw1 = bypw[1] * INV2PI;
        const float bb0 = bypb[0], bb1 = bypb[1];
        #pragma unroll
        for (int j = 0; j < 8; ++j) {
            const int t = t0 + tb + j;
            const float v = gelu_exact(acc[j]);
            float s = hw_sin_rev(fmaf(wsO, v, woO)) * bsO;
            const float xb = fmaf((float)t, lw, lb);
            s = fmaf(hw_sin_rev(fmaf(bw0, xb, bw1)), bb1, s);
            #pragma unroll
            for (int m = 1; m < 64; m <<= 1) s += __shfl_xor(s, m, 64);
            if (lane == 0) s_red[tb + j] = s + bcO + bb0;
        }
    }
    __syncthreads();
    if (tid < 32) out[(size_t)b * SEQ + t0 + tid] = s_red[tid];
}

extern "C" void kernel_launch(void* const* d_in, const int* in_sizes, int n_in,
                              void* d_out, int out_size, void* d_ws, size_t ws_size,
                              hipStream_t stream) {
    const float* x     = (const float*)d_in[0];
    const float* w0    = (const float*)d_in[1];
    const float* b0    = (const float*)d_in[2];
    const float* w1    = (const float*)d_in[3];
    const float* b1    = (const float*)d_in[4];
    const float* g1    = (const float*)d_in[5];
    const float* bln1  = (const float*)d_in[6];
    const float* w2    = (const float*)d_in[7];
    const float* b2    = (const float*)d_in[8];
    const float* g2    = (const float*)d_in[9];
    const float* bln2  = (const float*)d_in[10];
    const float* w3    = (const float*)d_in[11];
    const float* b3    = (const float*)d_in[12];
    const float* lcw   = (const float*)d_in[13];
    const float* lcb   = (const float*)d_in[14];
    const float* bypw  = (const float*)d_in[15];
    const float* bypb  = (const float*)d_in[16];
    float* out = (float*)d_out;
    float* ws  = (float*)d_ws;

    float* p0   = ws + OFF_P0;
    float* p1   = ws + OFF_P1;
    float* h1   = ws + OFF_H1;
    float* p2   = ws + OFF_P2;
    float* h2   = ws + OFF_H2;
    float* p3   = ws + OFF_P3;
    float* mlpT = ws + OFF_MLPT;

    k_gemm0 <<<dim3(16, 8),  256, 0, stream>>>(x,  w0, p0);
    k_gemm1 <<<dim3(16, 16), 256, 0, stream>>>(p0, b0, w1, p1);
    k_lng   <<<B_, 1024,     0, stream>>>(p1, b1, g1, bln1, h1);
    k_gemm2 <<<dim3(16, 16), 256, 0, stream>>>(h1, w2, p2);
    k_lng   <<<B_, 1024,     0, stream>>>(p2, b2, g2, bln2, h2);
    k_gemm3 <<<dim3(98, 8),  256, 0, stream>>>(h2, w3, p3);
    k_comb3T<<<dim3(98, B_), 256, 0, stream>>>(p3, b3, mlpT);
    k_ripple<<<dim3(SEQ / 32, B_), 256, 0, stream>>>(mlpT, lcw, lcb, bypw, bypb, out);
}